// Round 1
// baseline (877.074 us; speedup 1.0000x reference)
//
#include <hip/hip_runtime.h>
#include <math.h>

#define A_W 0.955f
#define B_W 1.3693f
#define INF_W 1e6f
#define HDIM 512
#define WDIM 512
#define NPIX (HDIM*WDIM)
#define NSAMP 16
#define NTOT_F 4194304.0f

// ws layout (bytes):
//  [0,256):    float acc[64]: [0]=focal_sum [1]=bnd_sum [2..17]=inter[s] [18..33]=sum_p+sum_t[s] [34..49]=mx[s]
//  [256,512):  int flags[64]: [0..15]=has_b[s] [16..31]=has_fg[s]
//  [1024, 1024+16MB): float d[16][512][512]  (seed prefill -> pass1 -> pass2, in place)

__global__ __launch_bounds__(128) void seed_kernel(const int* __restrict__ tg,
                                                   float* __restrict__ d,
                                                   int* __restrict__ flags) {
    const int s = blockIdx.x >> 9;
    const int r = blockIdx.x & 511;
    const int tid = threadIdx.x;
    const int c0 = tid * 4;
    const size_t sb = (size_t)s * NPIX;

    bool fg[6], bg[6];
#pragma unroll
    for (int j = 0; j < 6; ++j) { fg[j] = false; bg[j] = false; }
    int4 center = make_int4(0, 0, 0, 0);
#pragma unroll
    for (int dr = -1; dr <= 1; ++dr) {
        int rr = r + dr;
        if (rr < 0 || rr >= HDIM) continue;
        const int* rowp = tg + sb + (size_t)rr * WDIM;
        int4 cc = *(const int4*)(rowp + c0);
        if (dr == 0) center = cc;
        int vl = (c0 > 0) ? rowp[c0 - 1] : -1;        // -1 => outside grid (excluded)
        int vr = (c0 + 4 < WDIM) ? rowp[c0 + 4] : -1;
        int v[6] = {vl, cc.x, cc.y, cc.z, cc.w, vr};
#pragma unroll
        for (int j = 0; j < 6; ++j) {
            if (v[j] >= 0) { fg[j] = fg[j] || (v[j] != 0); bg[j] = bg[j] || (v[j] == 0); }
        }
    }
    float out[4];
    bool anyb = false;
#pragma unroll
    for (int i = 0; i < 4; ++i) {
        bool f = fg[i] || fg[i + 1] || fg[i + 2];
        bool b = bg[i] || bg[i + 1] || bg[i + 2];
        bool bd = f && b;               // dil==1 && ero==0
        anyb = anyb || bd;
        out[i] = bd ? 0.0f : INF_W;
    }
    bool anyfg = (center.x | center.y | center.z | center.w) != 0;
    *(float4*)(d + sb + (size_t)r * WDIM + c0) = make_float4(out[0], out[1], out[2], out[3]);

    if (__any((int)anyb)  && (tid & 63) == 0) atomicOr(&flags[s], 1);
    if (__any((int)anyfg) && (tid & 63) == 0) atomicOr(&flags[16 + s], 1);
}

// One wave per sample. Lane owns 8 logical columns [8*lane, 8*lane+7].
__global__ __launch_bounds__(64) void chamfer_kernel(const int* __restrict__ tg,
                                                     float* d,
                                                     const int* __restrict__ flags,
                                                     float* acc) {
    const int s = blockIdx.x;
    const int lane = threadIdx.x;
    const size_t sb = (size_t)s * NPIX;
    const bool useb = flags[s] != 0;
    const int c0 = lane * 8;

    float prev[8], drow[8], nxt[8];

    // ---------------- PASS 1 (top-down; cummin left->right) ----------------
    auto load1 = [&](int r, float* dst) {
        if (useb) {
            const float* p = d + sb + (size_t)r * WDIM + c0;
            float4 a = *(const float4*)p;
            float4 b = *(const float4*)(p + 4);
            dst[0]=a.x; dst[1]=a.y; dst[2]=a.z; dst[3]=a.w;
            dst[4]=b.x; dst[5]=b.y; dst[6]=b.z; dst[7]=b.w;
        } else {
            const int* p = tg + sb + (size_t)r * WDIM + c0;
            int4 a = *(const int4*)p;
            int4 b = *(const int4*)(p + 4);
            dst[0] = (a.x == 0) ? 0.f : INF_W;  dst[1] = (a.y == 0) ? 0.f : INF_W;
            dst[2] = (a.z == 0) ? 0.f : INF_W;  dst[3] = (a.w == 0) ? 0.f : INF_W;
            dst[4] = (b.x == 0) ? 0.f : INF_W;  dst[5] = (b.y == 0) ? 0.f : INF_W;
            dst[6] = (b.z == 0) ? 0.f : INF_W;  dst[7] = (b.w == 0) ? 0.f : INF_W;
        }
    };

#pragma unroll
    for (int i = 0; i < 8; ++i) prev[i] = INF_W;
    load1(0, drow);
    for (int r = 0; r < HDIM; ++r) {
        if (r + 1 < HDIM) load1(r + 1, nxt);   // prefetch next row (disjoint from store below)

        float lIn = __shfl_up(prev[7], 1);  if (lane == 0)  lIn = INF_W;
        float rIn = __shfl_down(prev[0], 1); if (lane == 63) rIn = INF_W;
        float cj[8];
        float run = INF_W;
#pragma unroll
        for (int i = 0; i < 8; ++i) {
            float up = prev[i] + A_W;
            float ul = ((i == 0) ? lIn : prev[i - 1]) + B_W;
            float ur = ((i == 7) ? rIn : prev[i + 1]) + B_W;
            float m = fminf(fminf(drow[i], up), fminf(ul, ur));
            float g = m - A_W * (float)(c0 + i);
            run = fminf(run, g);
            cj[i] = run;
        }
        float t = run;
#pragma unroll
        for (int off = 1; off < 64; off <<= 1) {
            float v = __shfl_up(t, off);
            if (lane >= off) t = fminf(t, v);
        }
        float ex = __shfl_up(t, 1); if (lane == 0) ex = INF_W;
        float cur[8];
#pragma unroll
        for (int i = 0; i < 8; ++i) {
            cur[i] = A_W * (float)(c0 + i) + fminf(cj[i], ex);
            prev[i] = cur[i];
        }
        float* p = d + sb + (size_t)r * WDIM + c0;
        *(float4*)p       = make_float4(cur[0], cur[1], cur[2], cur[3]);
        *(float4*)(p + 4) = make_float4(cur[4], cur[5], cur[6], cur[7]);
#pragma unroll
        for (int i = 0; i < 8; ++i) drow[i] = nxt[i];
    }

    __threadfence();
    __syncthreads();

    // ---------------- PASS 2 (bottom-up, flipped; in-place) ----------------
    auto load2 = [&](int r, float* dst) {
        int pr = HDIM - 1 - r;
        const float* p = d + sb + (size_t)pr * WDIM + (WDIM - 8 - c0);
        float4 a = *(const float4*)p;        // phys cols 504-c0..507-c0 = logical c0+7..c0+4
        float4 b = *(const float4*)(p + 4);  // phys cols 508-c0..511-c0 = logical c0+3..c0
        dst[7]=a.x; dst[6]=a.y; dst[5]=a.z; dst[4]=a.w;
        dst[3]=b.x; dst[2]=b.y; dst[1]=b.z; dst[0]=b.w;
    };

#pragma unroll
    for (int i = 0; i < 8; ++i) prev[i] = INF_W;
    float mx = 0.f;
    load2(0, drow);
    for (int r = 0; r < HDIM; ++r) {
        if (r + 1 < HDIM) load2(r + 1, nxt);

        float lIn = __shfl_up(prev[7], 1);  if (lane == 0)  lIn = INF_W;
        float rIn = __shfl_down(prev[0], 1); if (lane == 63) rIn = INF_W;
        float cj[8];
        float run = INF_W;
#pragma unroll
        for (int i = 0; i < 8; ++i) {
            float up = prev[i] + A_W;
            float ul = ((i == 0) ? lIn : prev[i - 1]) + B_W;
            float ur = ((i == 7) ? rIn : prev[i + 1]) + B_W;
            float m = fminf(fminf(drow[i], up), fminf(ul, ur));
            float g = m - A_W * (float)(c0 + i);
            run = fminf(run, g);
            cj[i] = run;
        }
        float t = run;
#pragma unroll
        for (int off = 1; off < 64; off <<= 1) {
            float v = __shfl_up(t, off);
            if (lane >= off) t = fminf(t, v);
        }
        float ex = __shfl_up(t, 1); if (lane == 0) ex = INF_W;
        float cur[8];
#pragma unroll
        for (int i = 0; i < 8; ++i) {
            cur[i] = A_W * (float)(c0 + i) + fminf(cj[i], ex);
            prev[i] = cur[i];
            mx = fmaxf(mx, cur[i]);
        }
        int pr = HDIM - 1 - r;
        float* p = d + sb + (size_t)pr * WDIM + (WDIM - 8 - c0);
        *(float4*)p       = make_float4(cur[7], cur[6], cur[5], cur[4]);
        *(float4*)(p + 4) = make_float4(cur[3], cur[2], cur[1], cur[0]);
#pragma unroll
        for (int i = 0; i < 8; ++i) drow[i] = nxt[i];
    }

#pragma unroll
    for (int off = 32; off > 0; off >>= 1) mx = fmaxf(mx, __shfl_xor(mx, off));
    if (lane == 0) acc[34 + s] = mx;
}

__global__ __launch_bounds__(256) void loss_kernel(const float* __restrict__ pred,
                                                   const int* __restrict__ tg,
                                                   const float* __restrict__ d,
                                                   const int* __restrict__ flags,
                                                   float* acc) {
    const int s = blockIdx.x >> 5;
    const int chunk = blockIdx.x & 31;
    const size_t base = (size_t)s * NPIX + (size_t)chunk * 8192;
    const float mxs = acc[34 + s];
    const bool hfg = flags[16 + s] != 0;
    const float scale = (mxs > 0.f) ? (1.f / fmaxf(mxs, 1e-12f)) : 1.f;
    const int tid = threadIdx.x;

    float facc = 0.f, bacc = 0.f, iacc = 0.f, pacc = 0.f;
    for (int it = 0; it < 8; ++it) {
        size_t idx = base + (size_t)(it * 256 + tid) * 4;
        float4 x4 = *(const float4*)(pred + idx);
        int4   t4 = *(const int4*)(tg + idx);
        float4 d4 = *(const float4*)(d + idx);
        float xs[4] = {x4.x, x4.y, x4.z, x4.w};
        int   ts[4] = {t4.x, t4.y, t4.z, t4.w};
        float dd[4] = {d4.x, d4.y, d4.z, d4.w};
#pragma unroll
        for (int i = 0; i < 4; ++i) {
            float x = xs[i];
            float e = __expf(-fabsf(x));
            float L = log1pf(e);                 // softplus(-|x|)
            float p = 1.f / (1.f + __expf(-x));
            bool t1 = ts[i] != 0;
            float fo = t1 ? 0.25f * (1.f - p) * (1.f - p) * (fmaxf(-x, 0.f) + L)
                          : 0.75f * p * p * (fmaxf(x, 0.f) + L);
            facc += fo;
            float dist = hfg ? dd[i] * scale : 1.f;
            bacc += (t1 ? (1.f - p) : p) * (1.f + dist);
            float tf = t1 ? 1.f : 0.f;
            iacc += tf * p;
            pacc += p + tf;
        }
    }
    __shared__ float red[4][4];
#pragma unroll
    for (int off = 32; off > 0; off >>= 1) {
        facc += __shfl_down(facc, off);
        bacc += __shfl_down(bacc, off);
        iacc += __shfl_down(iacc, off);
        pacc += __shfl_down(pacc, off);
    }
    int wave = tid >> 6;
    if ((tid & 63) == 0) { red[0][wave] = facc; red[1][wave] = bacc; red[2][wave] = iacc; red[3][wave] = pacc; }
    __syncthreads();
    if (tid == 0) {
        float f = 0, b = 0, i2 = 0, pp = 0;
        for (int w = 0; w < 4; ++w) { f += red[0][w]; b += red[1][w]; i2 += red[2][w]; pp += red[3][w]; }
        atomicAdd(&acc[0], f);
        atomicAdd(&acc[1], b);
        atomicAdd(&acc[2 + s], i2);
        atomicAdd(&acc[18 + s], pp);
    }
}

__global__ void final_kernel(const float* __restrict__ acc, const float* __restrict__ lv,
                             float* __restrict__ out) {
    if (threadIdx.x == 0) {
        float focal = acc[0] / NTOT_F;
        float bnd   = acc[1] / NTOT_F;
        float dsum = 0.f, isum = 0.f;
        for (int s = 0; s < NSAMP; ++s) {
            float inter = acc[2 + s];
            float tot   = acc[18 + s];
            dsum += (2.f * inter + 1e-6f) / (tot + 1e-6f);
            isum += (inter + 1e-6f) / (tot - inter + 1e-6f);
        }
        float dice = 1.f - dsum / 16.f;
        float iou  = 1.f - isum / 16.f;
        float l0 = lv[0], l1 = lv[1], l2 = lv[2], l3 = lv[3];
        float total = expf(-l0) * focal + l0 + expf(-l1) * dice + l1
                    + expf(-l2) * bnd  + l2 + expf(-l3) * iou  + l3;
        out[0] = total; out[1] = focal; out[2] = dice; out[3] = bnd; out[4] = iou;
    }
}

extern "C" void kernel_launch(void* const* d_in, const int* in_sizes, int n_in,
                              void* d_out, int out_size, void* d_ws, size_t ws_size,
                              hipStream_t stream) {
    const float* pred = (const float*)d_in[0];
    const int*   tg   = (const int*)d_in[1];
    const float* lv   = (const float*)d_in[2];
    float* out = (float*)d_out;
    char* ws = (char*)d_ws;
    float* acc   = (float*)ws;          // 64 floats
    int*   flags = (int*)(ws + 256);    // 64 ints
    float* d     = (float*)(ws + 1024); // 16 MB distance buffer

    hipMemsetAsync(d_ws, 0, 512, stream);
    seed_kernel<<<NSAMP * HDIM, 128, 0, stream>>>(tg, d, flags);
    chamfer_kernel<<<NSAMP, 64, 0, stream>>>(tg, d, flags, acc);
    loss_kernel<<<NSAMP * 32, 256, 0, stream>>>(pred, tg, d, flags, acc);
    final_kernel<<<1, 64, 0, stream>>>(acc, lv, out);
}

// Round 3
// 576.524 us; speedup vs baseline: 1.5213x; 1.5213x over previous
//
#include <hip/hip_runtime.h>
#include <math.h>

#define A_W 0.955f
#define B_W 1.3693f
#define INF_W 1e6f
#define HDIM 512
#define WDIM 512
#define NPIX (HDIM*WDIM)
#define NSAMP 16
#define NTOT_F 4194304.0f
#define PF 8   // prefetch depth == unroll factor

// ws layout (bytes):
//  [0,256):    float acc[64]: [0]=focal_sum [1]=bnd_sum [2..17]=inter[s] [18..33]=sum_p+sum_t[s] [34..49]=mx[s]
//  [256,512):  int flags[64]: [0..15]=has_b[s] [16..31]=has_fg[s]
//  [1024, 1024+16MB): float d[16][512][512]  (seed prefill -> pass1 -> pass2, in place)

// DPP move with INF fill for invalid lanes / masked rows.
// NOTE direction semantics (per LLVM AMDGPUAtomicOptimizer):
//   WAVE_SHR1 (0x138): lane i <- lane i-1  (data moves toward higher lanes; == __shfl_up by 1)
//   WAVE_SHL1 (0x130): lane i <- lane i+1  (data moves toward lower lanes;  == __shfl_down by 1)
template<int CTRL, int RMASK>
__device__ __forceinline__ float dpp_mov_inf(float x) {
    return __int_as_float(__builtin_amdgcn_update_dpp(
        __float_as_int(INF_W), __float_as_int(x), CTRL, RMASK, 0xF, false));
}

// Inclusive 64-lane prefix-min, pure VALU (DPP). row_shr 1/2/4/8 within rows of 16,
// then row_bcast15 (rows 1,3) and row_bcast31 (rows 2,3). Invalid lanes get INF (identity).
__device__ __forceinline__ float wave_prefix_min_incl(float t) {
    t = fminf(t, dpp_mov_inf<0x111,0xF>(t));   // row_shr:1
    t = fminf(t, dpp_mov_inf<0x112,0xF>(t));   // row_shr:2
    t = fminf(t, dpp_mov_inf<0x114,0xF>(t));   // row_shr:4
    t = fminf(t, dpp_mov_inf<0x118,0xF>(t));   // row_shr:8
    t = fminf(t, dpp_mov_inf<0x142,0xA>(t));   // row_bcast:15 -> rows 1,3
    t = fminf(t, dpp_mov_inf<0x143,0xC>(t));   // row_bcast:31 -> rows 2,3
    return t;
}

// One chamfer row-step. prev[] (in: previous row, out: current row result).
// drow[] = seed/min-candidate values for this row. jc[i] = A_W*(c0+i).
__device__ __forceinline__ void row_step(const float* jc, float* prev, const float* drow) {
    float lIn = dpp_mov_inf<0x138,0xF>(prev[7]);  // WAVE_SHR1: lane i <- lane i-1, lane0=INF
    float rIn = dpp_mov_inf<0x130,0xF>(prev[0]);  // WAVE_SHL1: lane i <- lane i+1, lane63=INF
    float g[8];
#pragma unroll
    for (int i = 0; i < 8; ++i) {
        float up = prev[i] + A_W;
        float ul = ((i == 0) ? lIn : prev[i-1]) + B_W;
        float ur = ((i == 7) ? rIn : prev[i+1]) + B_W;
        g[i] = fminf(fminf(drow[i], up), fminf(ul, ur)) - jc[i];
    }
    // Kogge-Stone inclusive prefix-min over the 8 lane-local elements (3-deep chain)
    float c1[8];
    c1[0] = g[0];
#pragma unroll
    for (int i = 1; i < 8; ++i) c1[i] = fminf(g[i], g[i-1]);
    float c2[8];
    c2[0] = c1[0]; c2[1] = c1[1];
#pragma unroll
    for (int i = 2; i < 8; ++i) c2[i] = fminf(c1[i], c1[i-2]);
    float cj[8];
    cj[0] = c2[0]; cj[1] = c2[1]; cj[2] = c2[2]; cj[3] = c2[3];
#pragma unroll
    for (int i = 4; i < 8; ++i) cj[i] = fminf(c2[i], c2[i-4]);
    // cross-lane exclusive prefix-min of lane totals
    float t  = wave_prefix_min_incl(cj[7]);
    float ex = dpp_mov_inf<0x138,0xF>(t);         // exclusive: WAVE_SHR1, lane0=INF
#pragma unroll
    for (int i = 0; i < 8; ++i) prev[i] = jc[i] + fminf(cj[i], ex);
}

__global__ __launch_bounds__(128) void seed_kernel(const int* __restrict__ tg,
                                                   float* __restrict__ d,
                                                   int* __restrict__ flags) {
    const int s = blockIdx.x >> 9;
    const int r = blockIdx.x & 511;
    const int tid = threadIdx.x;
    const int c0 = tid * 4;
    const size_t sb = (size_t)s * NPIX;

    bool fg[6], bg[6];
#pragma unroll
    for (int j = 0; j < 6; ++j) { fg[j] = false; bg[j] = false; }
    int4 center = make_int4(0, 0, 0, 0);
#pragma unroll
    for (int dr = -1; dr <= 1; ++dr) {
        int rr = r + dr;
        if (rr < 0 || rr >= HDIM) continue;
        const int* rowp = tg + sb + (size_t)rr * WDIM;
        int4 cc = *(const int4*)(rowp + c0);
        if (dr == 0) center = cc;
        int vl = (c0 > 0) ? rowp[c0 - 1] : -1;        // -1 => outside grid (excluded)
        int vr = (c0 + 4 < WDIM) ? rowp[c0 + 4] : -1;
        int v[6] = {vl, cc.x, cc.y, cc.z, cc.w, vr};
#pragma unroll
        for (int j = 0; j < 6; ++j) {
            if (v[j] >= 0) { fg[j] = fg[j] || (v[j] != 0); bg[j] = bg[j] || (v[j] == 0); }
        }
    }
    float out[4];
    bool anyb = false;
#pragma unroll
    for (int i = 0; i < 4; ++i) {
        bool f = fg[i] || fg[i + 1] || fg[i + 2];
        bool b = bg[i] || bg[i + 1] || bg[i + 2];
        bool bd = f && b;               // dil==1 && ero==0
        anyb = anyb || bd;
        out[i] = bd ? 0.0f : INF_W;
    }
    bool anyfg = (center.x | center.y | center.z | center.w) != 0;
    *(float4*)(d + sb + (size_t)r * WDIM + c0) = make_float4(out[0], out[1], out[2], out[3]);

    if (__any((int)anyb)  && (tid & 63) == 0) atomicOr(&flags[s], 1);
    if (__any((int)anyfg) && (tid & 63) == 0) atomicOr(&flags[16 + s], 1);
}

// One wave per sample. Lane owns 8 logical columns [8*lane, 8*lane+7].
__global__ __launch_bounds__(64) void chamfer_kernel(const int* __restrict__ tg,
                                                     float* d,
                                                     const int* __restrict__ flags,
                                                     float* acc) {
    const int s = blockIdx.x;
    const int lane = threadIdx.x;
    const size_t sb = (size_t)s * NPIX;
    const bool useb = flags[s] != 0;
    const int c0 = lane * 8;

    float jc[8];
#pragma unroll
    for (int i = 0; i < 8; ++i) jc[i] = A_W * (float)(c0 + i);

    float buf[PF][8], prev[8];

    // ---------------- PASS 1 (top-down; cummin left->right) ----------------
    auto load1 = [&](int r, float* dst) {
        if (useb) {
            const float* p = d + sb + (size_t)r * WDIM + c0;
            float4 a = *(const float4*)p;
            float4 b = *(const float4*)(p + 4);
            dst[0]=a.x; dst[1]=a.y; dst[2]=a.z; dst[3]=a.w;
            dst[4]=b.x; dst[5]=b.y; dst[6]=b.z; dst[7]=b.w;
        } else {
            const int* p = tg + sb + (size_t)r * WDIM + c0;
            int4 a = *(const int4*)p;
            int4 b = *(const int4*)(p + 4);
            dst[0] = (a.x == 0) ? 0.f : INF_W;  dst[1] = (a.y == 0) ? 0.f : INF_W;
            dst[2] = (a.z == 0) ? 0.f : INF_W;  dst[3] = (a.w == 0) ? 0.f : INF_W;
            dst[4] = (b.x == 0) ? 0.f : INF_W;  dst[5] = (b.y == 0) ? 0.f : INF_W;
            dst[6] = (b.z == 0) ? 0.f : INF_W;  dst[7] = (b.w == 0) ? 0.f : INF_W;
        }
    };

#pragma unroll
    for (int i = 0; i < 8; ++i) prev[i] = INF_W;
#pragma unroll
    for (int k = 0; k < PF; ++k) load1(k, buf[k]);

    for (int rb = 0; rb < HDIM; rb += PF) {
#pragma unroll
        for (int k = 0; k < PF; ++k) {
            const int r = rb + k;
            row_step(jc, prev, buf[k]);
            if (r + PF < HDIM) load1(r + PF, buf[k]);   // prefetch ~PF rows ahead
            float* p = d + sb + (size_t)r * WDIM + c0;
            *(float4*)p       = make_float4(prev[0], prev[1], prev[2], prev[3]);
            *(float4*)(p + 4) = make_float4(prev[4], prev[5], prev[6], prev[7]);
        }
    }

    __threadfence();
    __syncthreads();

    // ---------------- PASS 2 (bottom-up, flipped; in-place) ----------------
    auto load2 = [&](int r, float* dst) {
        int pr = HDIM - 1 - r;
        const float* p = d + sb + (size_t)pr * WDIM + (WDIM - 8 - c0);
        float4 a = *(const float4*)p;        // phys cols = logical c0+7..c0+4
        float4 b = *(const float4*)(p + 4);  // phys cols = logical c0+3..c0
        dst[7]=a.x; dst[6]=a.y; dst[5]=a.z; dst[4]=a.w;
        dst[3]=b.x; dst[2]=b.y; dst[1]=b.z; dst[0]=b.w;
    };

#pragma unroll
    for (int i = 0; i < 8; ++i) prev[i] = INF_W;
    float mx = 0.f;
#pragma unroll
    for (int k = 0; k < PF; ++k) load2(k, buf[k]);

    for (int rb = 0; rb < HDIM; rb += PF) {
#pragma unroll
        for (int k = 0; k < PF; ++k) {
            const int r = rb + k;
            row_step(jc, prev, buf[k]);
            if (r + PF < HDIM) load2(r + PF, buf[k]);
#pragma unroll
            for (int i = 0; i < 8; ++i) mx = fmaxf(mx, prev[i]);
            int pr = HDIM - 1 - r;
            float* p = d + sb + (size_t)pr * WDIM + (WDIM - 8 - c0);
            *(float4*)p       = make_float4(prev[7], prev[6], prev[5], prev[4]);
            *(float4*)(p + 4) = make_float4(prev[3], prev[2], prev[1], prev[0]);
        }
    }

#pragma unroll
    for (int off = 32; off > 0; off >>= 1) mx = fmaxf(mx, __shfl_xor(mx, off));
    if (lane == 0) acc[34 + s] = mx;
}

__global__ __launch_bounds__(256) void loss_kernel(const float* __restrict__ pred,
                                                   const int* __restrict__ tg,
                                                   const float* __restrict__ d,
                                                   const int* __restrict__ flags,
                                                   float* acc) {
    const int s = blockIdx.x >> 5;
    const int chunk = blockIdx.x & 31;
    const size_t base = (size_t)s * NPIX + (size_t)chunk * 8192;
    const float mxs = acc[34 + s];
    const bool hfg = flags[16 + s] != 0;
    const float scale = (mxs > 0.f) ? (1.f / fmaxf(mxs, 1e-12f)) : 1.f;
    const int tid = threadIdx.x;

    float facc = 0.f, bacc = 0.f, iacc = 0.f, pacc = 0.f;
    for (int it = 0; it < 8; ++it) {
        size_t idx = base + (size_t)(it * 256 + tid) * 4;
        float4 x4 = *(const float4*)(pred + idx);
        int4   t4 = *(const int4*)(tg + idx);
        float4 d4 = *(const float4*)(d + idx);
        float xs[4] = {x4.x, x4.y, x4.z, x4.w};
        int   ts[4] = {t4.x, t4.y, t4.z, t4.w};
        float dd[4] = {d4.x, d4.y, d4.z, d4.w};
#pragma unroll
        for (int i = 0; i < 4; ++i) {
            float x = xs[i];
            float e = __expf(-fabsf(x));       // e = exp(-|x|) in (0,1]
            float inv = 1.f / (1.f + e);
            float p = (x >= 0.f) ? inv : (1.f - inv);   // sigmoid(x)
            float L = __logf(1.f + e);                  // softplus(-|x|)
            bool t1 = ts[i] != 0;
            float fo = t1 ? 0.25f * (1.f - p) * (1.f - p) * (fmaxf(-x, 0.f) + L)
                          : 0.75f * p * p * (fmaxf(x, 0.f) + L);
            facc += fo;
            float dist = hfg ? dd[i] * scale : 1.f;
            bacc += (t1 ? (1.f - p) : p) * (1.f + dist);
            float tf = t1 ? 1.f : 0.f;
            iacc += tf * p;
            pacc += p + tf;
        }
    }
    __shared__ float red[4][4];
#pragma unroll
    for (int off = 32; off > 0; off >>= 1) {
        facc += __shfl_down(facc, off);
        bacc += __shfl_down(bacc, off);
        iacc += __shfl_down(iacc, off);
        pacc += __shfl_down(pacc, off);
    }
    int wave = tid >> 6;
    if ((tid & 63) == 0) { red[0][wave] = facc; red[1][wave] = bacc; red[2][wave] = iacc; red[3][wave] = pacc; }
    __syncthreads();
    if (tid == 0) {
        float f = 0, b = 0, i2 = 0, pp = 0;
        for (int w = 0; w < 4; ++w) { f += red[0][w]; b += red[1][w]; i2 += red[2][w]; pp += red[3][w]; }
        atomicAdd(&acc[0], f);
        atomicAdd(&acc[1], b);
        atomicAdd(&acc[2 + s], i2);
        atomicAdd(&acc[18 + s], pp);
    }
}

__global__ void final_kernel(const float* __restrict__ acc, const float* __restrict__ lv,
                             float* __restrict__ out) {
    if (threadIdx.x == 0) {
        float focal = acc[0] / NTOT_F;
        float bnd   = acc[1] / NTOT_F;
        float dsum = 0.f, isum = 0.f;
        for (int s = 0; s < NSAMP; ++s) {
            float inter = acc[2 + s];
            float tot   = acc[18 + s];
            dsum += (2.f * inter + 1e-6f) / (tot + 1e-6f);
            isum += (inter + 1e-6f) / (tot - inter + 1e-6f);
        }
        float dice = 1.f - dsum / 16.f;
        float iou  = 1.f - isum / 16.f;
        float l0 = lv[0], l1 = lv[1], l2 = lv[2], l3 = lv[3];
        float total = expf(-l0) * focal + l0 + expf(-l1) * dice + l1
                    + expf(-l2) * bnd  + l2 + expf(-l3) * iou  + l3;
        out[0] = total; out[1] = focal; out[2] = dice; out[3] = bnd; out[4] = iou;
    }
}

extern "C" void kernel_launch(void* const* d_in, const int* in_sizes, int n_in,
                              void* d_out, int out_size, void* d_ws, size_t ws_size,
                              hipStream_t stream) {
    const float* pred = (const float*)d_in[0];
    const int*   tg   = (const int*)d_in[1];
    const float* lv   = (const float*)d_in[2];
    float* out = (float*)d_out;
    char* ws = (char*)d_ws;
    float* acc   = (float*)ws;          // 64 floats
    int*   flags = (int*)(ws + 256);    // 64 ints
    float* d     = (float*)(ws + 1024); // 16 MB distance buffer

    hipMemsetAsync(d_ws, 0, 512, stream);
    seed_kernel<<<NSAMP * HDIM, 128, 0, stream>>>(tg, d, flags);
    chamfer_kernel<<<NSAMP, 64, 0, stream>>>(tg, d, flags, acc);
    loss_kernel<<<NSAMP * 32, 256, 0, stream>>>(pred, tg, d, flags, acc);
    final_kernel<<<1, 64, 0, stream>>>(acc, lv, out);
}

// Round 4
// 568.558 us; speedup vs baseline: 1.5426x; 1.0140x over previous
//
#include <hip/hip_runtime.h>
#include <math.h>

#define A_W 0.955f
#define B_W 1.3693f
#define INF_W 1e6f
#define HDIM 512
#define WDIM 512
#define NPIX (HDIM*WDIM)
#define NSAMP 16
#define NTOT_F 4194304.0f
#define PF 8   // prefetch depth == unroll factor

// ws layout (bytes):
//  [0,256):    float acc[64]: [0]=focal_sum [1]=bnd_sum [2..17]=inter[s] [18..33]=sum_p+sum_t[s] [34..49]=mx[s]
//  [256,512):  int flags[64]: [0..15]=has_b[s] [16..31]=has_fg[s]
//  [1024, 1024+16MB):       float dA[16][512][512]  (seeds -> final DT)
//  [1024+16MB, 1024+32MB):  float dB[16][512][512]  (pass-1 intermediate)

// DPP move with INF fill for invalid lanes / masked rows.
//   WAVE_SHR1 (0x138): lane i <- lane i-1  (== __shfl_up 1)
//   WAVE_SHL1 (0x130): lane i <- lane i+1  (== __shfl_down 1)
template<int CTRL, int RMASK>
__device__ __forceinline__ float dpp_mov_inf(float x) {
    return __int_as_float(__builtin_amdgcn_update_dpp(
        __float_as_int(INF_W), __float_as_int(x), CTRL, RMASK, 0xF, false));
}

// Inclusive 64-lane prefix-min, pure VALU (DPP).
__device__ __forceinline__ float wave_prefix_min_incl(float t) {
    t = fminf(t, dpp_mov_inf<0x111,0xF>(t));   // row_shr:1
    t = fminf(t, dpp_mov_inf<0x112,0xF>(t));   // row_shr:2
    t = fminf(t, dpp_mov_inf<0x114,0xF>(t));   // row_shr:4
    t = fminf(t, dpp_mov_inf<0x118,0xF>(t));   // row_shr:8
    t = fminf(t, dpp_mov_inf<0x142,0xA>(t));   // row_bcast:15 -> rows 1,3
    t = fminf(t, dpp_mov_inf<0x143,0xC>(t));   // row_bcast:31 -> rows 2,3
    return t;
}

// One chamfer row-step. prev[] (in: previous row, out: current row result).
__device__ __forceinline__ void row_step(const float* jc, float* prev, const float* drow) {
    float lIn = dpp_mov_inf<0x138,0xF>(prev[7]);  // lane i <- lane i-1, lane0=INF
    float rIn = dpp_mov_inf<0x130,0xF>(prev[0]);  // lane i <- lane i+1, lane63=INF
    float g[8];
#pragma unroll
    for (int i = 0; i < 8; ++i) {
        float up = prev[i] + A_W;
        float ul = ((i == 0) ? lIn : prev[i-1]) + B_W;
        float ur = ((i == 7) ? rIn : prev[i+1]) + B_W;
        g[i] = fminf(fminf(drow[i], up), fminf(ul, ur)) - jc[i];
    }
    // Kogge-Stone inclusive prefix-min over 8 lane-local elements
    float c1[8];
    c1[0] = g[0];
#pragma unroll
    for (int i = 1; i < 8; ++i) c1[i] = fminf(g[i], g[i-1]);
    float c2[8];
    c2[0] = c1[0]; c2[1] = c1[1];
#pragma unroll
    for (int i = 2; i < 8; ++i) c2[i] = fminf(c1[i], c1[i-2]);
    float cj[8];
    cj[0] = c2[0]; cj[1] = c2[1]; cj[2] = c2[2]; cj[3] = c2[3];
#pragma unroll
    for (int i = 4; i < 8; ++i) cj[i] = fminf(c2[i], c2[i-4]);
    // cross-lane exclusive prefix-min of lane totals
    float t  = wave_prefix_min_incl(cj[7]);
    float ex = dpp_mov_inf<0x138,0xF>(t);
#pragma unroll
    for (int i = 0; i < 8; ++i) prev[i] = jc[i] + fminf(cj[i], ex);
}

__global__ __launch_bounds__(128) void seed_kernel(const int* __restrict__ tg,
                                                   float* __restrict__ d,
                                                   int* __restrict__ flags) {
    const int s = blockIdx.x >> 9;
    const int r = blockIdx.x & 511;
    const int tid = threadIdx.x;
    const int c0 = tid * 4;
    const size_t sb = (size_t)s * NPIX;

    bool fg[6], bg[6];
#pragma unroll
    for (int j = 0; j < 6; ++j) { fg[j] = false; bg[j] = false; }
    int4 center = make_int4(0, 0, 0, 0);
#pragma unroll
    for (int dr = -1; dr <= 1; ++dr) {
        int rr = r + dr;
        if (rr < 0 || rr >= HDIM) continue;
        const int* rowp = tg + sb + (size_t)rr * WDIM;
        int4 cc = *(const int4*)(rowp + c0);
        if (dr == 0) center = cc;
        int vl = (c0 > 0) ? rowp[c0 - 1] : -1;        // -1 => outside grid (excluded)
        int vr = (c0 + 4 < WDIM) ? rowp[c0 + 4] : -1;
        int v[6] = {vl, cc.x, cc.y, cc.z, cc.w, vr};
#pragma unroll
        for (int j = 0; j < 6; ++j) {
            if (v[j] >= 0) { fg[j] = fg[j] || (v[j] != 0); bg[j] = bg[j] || (v[j] == 0); }
        }
    }
    float out[4];
    bool anyb = false;
#pragma unroll
    for (int i = 0; i < 4; ++i) {
        bool f = fg[i] || fg[i + 1] || fg[i + 2];
        bool b = bg[i] || bg[i + 1] || bg[i + 2];
        bool bd = f && b;               // dil==1 && ero==0
        anyb = anyb || bd;
        out[i] = bd ? 0.0f : INF_W;
    }
    bool anyfg = (center.x | center.y | center.z | center.w) != 0;
    *(float4*)(d + sb + (size_t)r * WDIM + c0) = make_float4(out[0], out[1], out[2], out[3]);

    if (__any((int)anyb)  && (tid & 63) == 0) atomicOr(&flags[s], 1);
    if (__any((int)anyfg) && (tid & 63) == 0) atomicOr(&flags[16 + s], 1);
}

// PASS 1 (top-down). Reads seeds from dA (or tg), writes rows to dB. No aliasing.
__global__ __launch_bounds__(64) void chamfer1_kernel(const int* __restrict__ tg,
                                                      const float* __restrict__ dA,
                                                      float* __restrict__ dB,
                                                      const int* __restrict__ flags) {
    const int s = blockIdx.x;
    const int lane = threadIdx.x;
    const size_t sb = (size_t)s * NPIX;
    const bool useb = flags[s] != 0;
    const int c0 = lane * 8;

    float jc[8];
#pragma unroll
    for (int i = 0; i < 8; ++i) jc[i] = A_W * (float)(c0 + i);

    float buf[PF][8], prev[8];

    auto load1 = [&](int r, float* dst) {
        if (useb) {
            const float* p = dA + sb + (size_t)r * WDIM + c0;
            float4 a = *(const float4*)p;
            float4 b = *(const float4*)(p + 4);
            dst[0]=a.x; dst[1]=a.y; dst[2]=a.z; dst[3]=a.w;
            dst[4]=b.x; dst[5]=b.y; dst[6]=b.z; dst[7]=b.w;
        } else {
            const int* p = tg + sb + (size_t)r * WDIM + c0;
            int4 a = *(const int4*)p;
            int4 b = *(const int4*)(p + 4);
            dst[0] = (a.x == 0) ? 0.f : INF_W;  dst[1] = (a.y == 0) ? 0.f : INF_W;
            dst[2] = (a.z == 0) ? 0.f : INF_W;  dst[3] = (a.w == 0) ? 0.f : INF_W;
            dst[4] = (b.x == 0) ? 0.f : INF_W;  dst[5] = (b.y == 0) ? 0.f : INF_W;
            dst[6] = (b.z == 0) ? 0.f : INF_W;  dst[7] = (b.w == 0) ? 0.f : INF_W;
        }
    };

#pragma unroll
    for (int i = 0; i < 8; ++i) prev[i] = INF_W;
#pragma unroll
    for (int k = 0; k < PF; ++k) load1(k, buf[k]);

    for (int rb = 0; rb < HDIM; rb += PF) {
#pragma unroll
        for (int k = 0; k < PF; ++k) {
            const int r = rb + k;
            row_step(jc, prev, buf[k]);
            if (r + PF < HDIM) load1(r + PF, buf[k]);   // prefetch ~PF rows ahead
            float* p = dB + sb + (size_t)r * WDIM + c0;
            *(float4*)p       = make_float4(prev[0], prev[1], prev[2], prev[3]);
            *(float4*)(p + 4) = make_float4(prev[4], prev[5], prev[6], prev[7]);
        }
    }
}

// PASS 2 (bottom-up, flipped). Reads dB, writes final DT to dA. No aliasing.
__global__ __launch_bounds__(64) void chamfer2_kernel(const float* __restrict__ dB,
                                                      float* __restrict__ dA,
                                                      float* __restrict__ acc) {
    const int s = blockIdx.x;
    const int lane = threadIdx.x;
    const size_t sb = (size_t)s * NPIX;
    const int c0 = lane * 8;

    float jc[8];
#pragma unroll
    for (int i = 0; i < 8; ++i) jc[i] = A_W * (float)(c0 + i);

    float buf[PF][8], prev[8];

    auto load2 = [&](int r, float* dst) {
        int pr = HDIM - 1 - r;
        const float* p = dB + sb + (size_t)pr * WDIM + (WDIM - 8 - c0);
        float4 a = *(const float4*)p;        // phys cols = logical c0+7..c0+4
        float4 b = *(const float4*)(p + 4);  // phys cols = logical c0+3..c0
        dst[7]=a.x; dst[6]=a.y; dst[5]=a.z; dst[4]=a.w;
        dst[3]=b.x; dst[2]=b.y; dst[1]=b.z; dst[0]=b.w;
    };

#pragma unroll
    for (int i = 0; i < 8; ++i) prev[i] = INF_W;
    float mx = 0.f;
#pragma unroll
    for (int k = 0; k < PF; ++k) load2(k, buf[k]);

    for (int rb = 0; rb < HDIM; rb += PF) {
#pragma unroll
        for (int k = 0; k < PF; ++k) {
            const int r = rb + k;
            row_step(jc, prev, buf[k]);
            if (r + PF < HDIM) load2(r + PF, buf[k]);
#pragma unroll
            for (int i = 0; i < 8; ++i) mx = fmaxf(mx, prev[i]);
            int pr = HDIM - 1 - r;
            float* p = dA + sb + (size_t)pr * WDIM + (WDIM - 8 - c0);
            *(float4*)p       = make_float4(prev[7], prev[6], prev[5], prev[4]);
            *(float4*)(p + 4) = make_float4(prev[3], prev[2], prev[1], prev[0]);
        }
    }

#pragma unroll
    for (int off = 32; off > 0; off >>= 1) mx = fmaxf(mx, __shfl_xor(mx, off));
    if (lane == 0) acc[34 + s] = mx;
}

__global__ __launch_bounds__(256) void loss_kernel(const float* __restrict__ pred,
                                                   const int* __restrict__ tg,
                                                   const float* __restrict__ d,
                                                   const int* __restrict__ flags,
                                                   float* acc) {
    const int s = blockIdx.x >> 5;
    const int chunk = blockIdx.x & 31;
    const size_t base = (size_t)s * NPIX + (size_t)chunk * 8192;
    const float mxs = acc[34 + s];
    const bool hfg = flags[16 + s] != 0;
    const float scale = (mxs > 0.f) ? (1.f / fmaxf(mxs, 1e-12f)) : 1.f;
    const int tid = threadIdx.x;

    float facc = 0.f, bacc = 0.f, iacc = 0.f, pacc = 0.f;
    for (int it = 0; it < 8; ++it) {
        size_t idx = base + (size_t)(it * 256 + tid) * 4;
        float4 x4 = *(const float4*)(pred + idx);
        int4   t4 = *(const int4*)(tg + idx);
        float4 d4 = *(const float4*)(d + idx);
        float xs[4] = {x4.x, x4.y, x4.z, x4.w};
        int   ts[4] = {t4.x, t4.y, t4.z, t4.w};
        float dd[4] = {d4.x, d4.y, d4.z, d4.w};
#pragma unroll
        for (int i = 0; i < 4; ++i) {
            float x = xs[i];
            float e = __expf(-fabsf(x));       // e = exp(-|x|) in (0,1]
            float inv = 1.f / (1.f + e);
            float p = (x >= 0.f) ? inv : (1.f - inv);   // sigmoid(x)
            float L = __logf(1.f + e);                  // softplus(-|x|)
            bool t1 = ts[i] != 0;
            float fo = t1 ? 0.25f * (1.f - p) * (1.f - p) * (fmaxf(-x, 0.f) + L)
                          : 0.75f * p * p * (fmaxf(x, 0.f) + L);
            facc += fo;
            float dist = hfg ? dd[i] * scale : 1.f;
            bacc += (t1 ? (1.f - p) : p) * (1.f + dist);
            float tf = t1 ? 1.f : 0.f;
            iacc += tf * p;
            pacc += p + tf;
        }
    }
    __shared__ float red[4][4];
#pragma unroll
    for (int off = 32; off > 0; off >>= 1) {
        facc += __shfl_down(facc, off);
        bacc += __shfl_down(bacc, off);
        iacc += __shfl_down(iacc, off);
        pacc += __shfl_down(pacc, off);
    }
    int wave = tid >> 6;
    if ((tid & 63) == 0) { red[0][wave] = facc; red[1][wave] = bacc; red[2][wave] = iacc; red[3][wave] = pacc; }
    __syncthreads();
    if (tid == 0) {
        float f = 0, b = 0, i2 = 0, pp = 0;
        for (int w = 0; w < 4; ++w) { f += red[0][w]; b += red[1][w]; i2 += red[2][w]; pp += red[3][w]; }
        atomicAdd(&acc[0], f);
        atomicAdd(&acc[1], b);
        atomicAdd(&acc[2 + s], i2);
        atomicAdd(&acc[18 + s], pp);
    }
}

__global__ void final_kernel(const float* __restrict__ acc, const float* __restrict__ lv,
                             float* __restrict__ out) {
    if (threadIdx.x == 0) {
        float focal = acc[0] / NTOT_F;
        float bnd   = acc[1] / NTOT_F;
        float dsum = 0.f, isum = 0.f;
        for (int s = 0; s < NSAMP; ++s) {
            float inter = acc[2 + s];
            float tot   = acc[18 + s];
            dsum += (2.f * inter + 1e-6f) / (tot + 1e-6f);
            isum += (inter + 1e-6f) / (tot - inter + 1e-6f);
        }
        float dice = 1.f - dsum / 16.f;
        float iou  = 1.f - isum / 16.f;
        float l0 = lv[0], l1 = lv[1], l2 = lv[2], l3 = lv[3];
        float total = expf(-l0) * focal + l0 + expf(-l1) * dice + l1
                    + expf(-l2) * bnd  + l2 + expf(-l3) * iou  + l3;
        out[0] = total; out[1] = focal; out[2] = dice; out[3] = bnd; out[4] = iou;
    }
}

extern "C" void kernel_launch(void* const* d_in, const int* in_sizes, int n_in,
                              void* d_out, int out_size, void* d_ws, size_t ws_size,
                              hipStream_t stream) {
    const float* pred = (const float*)d_in[0];
    const int*   tg   = (const int*)d_in[1];
    const float* lv   = (const float*)d_in[2];
    float* out = (float*)d_out;
    char* ws = (char*)d_ws;
    float* acc   = (float*)ws;                          // 64 floats
    int*   flags = (int*)(ws + 256);                    // 64 ints
    float* dA    = (float*)(ws + 1024);                 // 16 MB (seeds -> final DT)
    float* dB    = (float*)(ws + 1024 + (size_t)NSAMP * NPIX * 4);  // 16 MB (pass-1)

    hipMemsetAsync(d_ws, 0, 512, stream);
    seed_kernel<<<NSAMP * HDIM, 128, 0, stream>>>(tg, dA, flags);
    chamfer1_kernel<<<NSAMP, 64, 0, stream>>>(tg, dA, dB, flags);
    chamfer2_kernel<<<NSAMP, 64, 0, stream>>>(dB, dA, acc);
    loss_kernel<<<NSAMP * 32, 256, 0, stream>>>(pred, tg, dA, flags, acc);
    final_kernel<<<1, 64, 0, stream>>>(acc, lv, out);
}